// Round 1
// baseline (845.197 us; speedup 1.0000x reference)
//
#include <hip/hip_runtime.h>
#include <hip/hip_bf16.h>
#include <cstdint>
#include <cstddef>

// minLSTM: out = exp(heinsen_scan(log_f, log_i + log_g(h))), [h,f,i] = x @ W
// B=4 S=8192 D=1024. GEMM in bf16 MFMA (fp32 accum), scan in fp32 log-space
// with the bounded recurrence log_h = logaddexp(log_h + lf, lv).

#define BB 4
#define SS 8192
#define DD 1024
#define MM 32768   // B*S
#define KK 1024    // D
#define NN 3072    // 3*D
#define CHUNKS 64
#define CLEN 128   // SS / CHUNKS
#define NCH 4096   // B*D channels

typedef __bf16 bf16;
typedef __bf16 bf16x4 __attribute__((ext_vector_type(4)));
typedef __bf16 bf16x8 __attribute__((ext_vector_type(8)));
typedef float f32x4 __attribute__((ext_vector_type(4)));

// ---- async global->LDS, 16B per lane (wave-uniform LDS base + lane*16) ----
__device__ __forceinline__ void gload16(const bf16* g, bf16* l) {
  __builtin_amdgcn_global_load_lds(
      (const __attribute__((address_space(1))) unsigned int*)(const void*)g,
      (__attribute__((address_space(3))) unsigned int*)(void*)l,
      16, 0, 0);
}

// ---- scalar math helpers (fast hw transcendentals; tolerance is bf16-scale) --
__device__ __forceinline__ float sp(float x) {  // softplus, stable
  return fmaxf(x, 0.f) + __logf(1.f + __expf(-fabsf(x)));
}
__device__ __forceinline__ void gates(float h, float f, float i,
                                      float& lf, float& lv) {
  float d = sp(-f) - sp(-i);
  float spd = sp(d);
  lf = -spd;            // -softplus(diff)
  float li = d - spd;   // -softplus(-diff)
  float lg = (h >= 0.f) ? __logf(h + 0.5f) : -sp(-h);
  lv = li + lg;
}
__device__ __forceinline__ float laddexp(float a, float b) {
  float m = fmaxf(a, b);
  return m + __logf(1.f + __expf(fminf(a, b) - m));
}

// ---- convert x fp32 -> bf16 (vectorized) ----
__global__ __launch_bounds__(256) void k_cvt_x(const float4* __restrict__ x,
                                               bf16x4* __restrict__ xb) {
  int i = blockIdx.x * 256 + threadIdx.x;
  float4 v = x[i];
  bf16x4 o;
  o[0] = (bf16)v.x; o[1] = (bf16)v.y; o[2] = (bf16)v.z; o[3] = (bf16)v.w;
  xb[i] = o;
}

// ---- convert + transpose W [K,N] fp32 -> Wt [N,K] bf16 (LDS 32x32 tile) ----
__global__ __launch_bounds__(256) void k_cvt_wt(const float* __restrict__ W,
                                                bf16* __restrict__ Wt) {
  __shared__ float tile[32][33];
  int n0 = blockIdx.x * 32, k0 = blockIdx.y * 32;
  int tx = threadIdx.x, ty = threadIdx.y;  // (32, 8)
#pragma unroll
  for (int i = 0; i < 32; i += 8)
    tile[ty + i][tx] = W[(size_t)(k0 + ty + i) * NN + n0 + tx];
  __syncthreads();
#pragma unroll
  for (int i = 0; i < 32; i += 8)
    Wt[(size_t)(n0 + ty + i) * KK + k0 + tx] = (bf16)tile[tx][ty + i];
}

// ---- bf16 GEMM, C[m][n] = sum_k A[m][k]*Bt[n][k]; 128x128 tile, BK=32 ------
// m97 structure: global_load_lds dwordx4 staging, 16x16x32 MFMA, 4 waves,
// each wave a 64x64 subtile (4x4 fragments).
template <typename TOut>
__global__ __launch_bounds__(256) void k_gemm(const bf16* __restrict__ A,
                                              const bf16* __restrict__ Bt,
                                              TOut* __restrict__ C) {
  __shared__ bf16 As[128 * 32];
  __shared__ bf16 Bs[128 * 32];
  const int tid = threadIdx.x;
  const int nBase = blockIdx.x * 128;
  const int mBase = blockIdx.y * 128;
  const int lane = tid & 63;
  const int w = tid >> 6;
  const int wm = (w >> 1) * 64, wn = (w & 1) * 64;
  const int col16 = lane & 15;       // m (A) / n (B) / col (C)
  const int kq = (lane >> 4) * 8;    // k quad offset
  const int r0 = tid >> 2;           // staging row 0..63
  const int cc = (tid & 3) * 8;      // staging col (elems)
  const bf16* ga0 = A + (size_t)(mBase + r0) * KK + cc;
  const bf16* ga1 = A + (size_t)(mBase + 64 + r0) * KK + cc;
  const bf16* gb0 = Bt + (size_t)(nBase + r0) * KK + cc;
  const bf16* gb1 = Bt + (size_t)(nBase + 64 + r0) * KK + cc;
  bf16* la = As + tid * 8;  // per-wave-contiguous: byte = w*1024 + lane*16
  bf16* lb = Bs + tid * 8;

  f32x4 acc[4][4];
#pragma unroll
  for (int mi = 0; mi < 4; ++mi)
#pragma unroll
    for (int ni = 0; ni < 4; ++ni)
      acc[mi][ni] = (f32x4){0.f, 0.f, 0.f, 0.f};

  for (int k0 = 0; k0 < KK; k0 += 32) {
    gload16(ga0 + k0, la);
    gload16(ga1 + k0, la + 2048);
    gload16(gb0 + k0, lb);
    gload16(gb1 + k0, lb + 2048);
    __syncthreads();  // drains vmcnt (async LDS writes) + barrier
    bf16x8 afr[4], bfr[4];
#pragma unroll
    for (int mi = 0; mi < 4; ++mi)
      afr[mi] = *(const bf16x8*)(As + (wm + mi * 16 + col16) * 32 + kq);
#pragma unroll
    for (int ni = 0; ni < 4; ++ni)
      bfr[ni] = *(const bf16x8*)(Bs + (wn + ni * 16 + col16) * 32 + kq);
#pragma unroll
    for (int mi = 0; mi < 4; ++mi)
#pragma unroll
      for (int ni = 0; ni < 4; ++ni)
        acc[mi][ni] = __builtin_amdgcn_mfma_f32_16x16x32_bf16(
            afr[mi], bfr[ni], acc[mi][ni], 0, 0, 0);
    __syncthreads();  // reads done before next stage overwrites
  }
  // C/D layout: col = lane&15, row = (lane>>4)*4 + reg  [m89-verified]
  const int rowq = (lane >> 4) * 4;
#pragma unroll
  for (int mi = 0; mi < 4; ++mi)
#pragma unroll
    for (int ni = 0; ni < 4; ++ni)
#pragma unroll
      for (int r = 0; r < 4; ++r) {
        int gm = mBase + wm + mi * 16 + rowq + r;
        int gn = nBase + wn + ni * 16 + col16;
        C[(size_t)gm * NN + gn] = (TOut)acc[mi][ni][r];
      }
}

// ---- scan phase 1: per (channel, chunk) aggregate (A = sum lf, V = local) --
template <typename THW>
__global__ __launch_bounds__(256) void k_scan1(const THW* __restrict__ hW,
                                               float2* __restrict__ agg) {
  const int d = blockIdx.x * 256 + threadIdx.x;
  const int b = blockIdx.y, c = blockIdx.z;
  const THW* p = hW + (size_t)(b * SS + c * CLEN) * NN + d;
  float A = 0.f, V = -1e30f;
  for (int j = 0; j < CLEN; ++j) {
    float h = (float)p[0], f = (float)p[DD], ii = (float)p[2 * DD];
    float lf, lv;
    gates(h, f, ii, lf, lv);
    A += lf;
    V = laddexp(V + lf, lv);
    p += NN;
  }
  agg[(size_t)c * NCH + b * DD + d] = make_float2(A, V);
}

// ---- scan phase 2: exclusive prefix over chunks, one thread per channel ----
__global__ __launch_bounds__(256) void k_scan2(const float2* __restrict__ agg,
                                               float2* __restrict__ pre) {
  const int ch = blockIdx.x * 256 + threadIdx.x;
  float A = 0.f, V = -1e30f;
  for (int c = 0; c < CHUNKS; ++c) {
    pre[(size_t)c * NCH + ch] = make_float2(A, V);
    float2 ag = agg[(size_t)c * NCH + ch];
    V = laddexp(ag.y, ag.x + V);
    A += ag.x;
  }
}

// ---- scan phase 3: re-run chunk with prefix init, write exp(log_h) ---------
template <typename THW>
__global__ __launch_bounds__(256) void k_scan3(const THW* __restrict__ hW,
                                               const float2* __restrict__ pre,
                                               float* __restrict__ out) {
  const int d = blockIdx.x * 256 + threadIdx.x;
  const int b = blockIdx.y, c = blockIdx.z;
  const THW* p = hW + (size_t)(b * SS + c * CLEN) * NN + d;
  float* o = out + (size_t)(b * SS + c * CLEN) * DD + d;
  float V = pre[(size_t)c * NCH + b * DD + d].y;
  for (int j = 0; j < CLEN; ++j) {
    float h = (float)p[0], f = (float)p[DD], ii = (float)p[2 * DD];
    float lf, lv;
    gates(h, f, ii, lf, lv);
    V = laddexp(V + lf, lv);
    *o = __expf(V);
    p += NN;
    o += DD;
  }
}

extern "C" void kernel_launch(void* const* d_in, const int* in_sizes, int n_in,
                              void* d_out, int out_size, void* d_ws,
                              size_t ws_size, hipStream_t stream) {
  const float* x = (const float*)d_in[0];
  const float* W = (const float*)d_in[1];
  float* out = (float*)d_out;
  char* ws = (char*)d_ws;

  // workspace layout
  const size_t wtB = (size_t)NN * KK * 2;   //  6,291,456
  const size_t xbB = (size_t)MM * KK * 2;   // 67,108,864
  const size_t hwF32 = (size_t)MM * NN * 4; // 402,653,184
  const size_t hwB16 = (size_t)MM * NN * 2; // 201,326,592
  const size_t aggB = (size_t)CHUNKS * NCH * sizeof(float2);  // 2 MiB
  bf16* Wt = (bf16*)ws;
  bf16* xb = (bf16*)(ws + wtB);
  char* hWp = ws + wtB + xbB;
  const bool f32path = ws_size >= wtB + xbB + hwF32 + 2 * aggB;

  k_cvt_wt<<<dim3(NN / 32, KK / 32), dim3(32, 8), 0, stream>>>(W, Wt);
  k_cvt_x<<<dim3(MM * KK / 4 / 256), dim3(256), 0, stream>>>((const float4*)x,
                                                             (bf16x4*)xb);
  if (f32path) {
    float* hW = (float*)hWp;
    float2* agg = (float2*)(hWp + hwF32);
    float2* pre = (float2*)(hWp + hwF32 + aggB);
    k_gemm<float><<<dim3(NN / 128, MM / 128), 256, 0, stream>>>(xb, Wt, hW);
    k_scan1<float><<<dim3(DD / 256, BB, CHUNKS), 256, 0, stream>>>(hW, agg);
    k_scan2<<<dim3(NCH / 256), 256, 0, stream>>>(agg, pre);
    k_scan3<float><<<dim3(DD / 256, BB, CHUNKS), 256, 0, stream>>>(hW, pre, out);
  } else {
    bf16* hW = (bf16*)hWp;
    float2* agg = (float2*)(hWp + hwB16);
    float2* pre = (float2*)(hWp + hwB16 + aggB);
    k_gemm<bf16><<<dim3(NN / 128, MM / 128), 256, 0, stream>>>(xb, Wt, hW);
    k_scan1<bf16><<<dim3(DD / 256, BB, CHUNKS), 256, 0, stream>>>(hW, agg);
    k_scan2<<<dim3(NCH / 256), 256, 0, stream>>>(agg, pre);
    k_scan3<bf16><<<dim3(DD / 256, BB, CHUNKS), 256, 0, stream>>>(hW, pre, out);
  }
}

// Round 2
// 744.659 us; speedup vs baseline: 1.1350x; 1.1350x over previous
//
#include <hip/hip_runtime.h>
#include <hip/hip_bf16.h>
#include <cstdint>
#include <cstddef>

// minLSTM: out = exp(heinsen_scan(log_f, log_i + log_g(h))), [h,f,i] = x @ W
// B=4 S=8192 D=1024. GEMM bf16 MFMA (fp32 accum) -> bf16 hW; fp32 log-space
// chunked scan with recurrence log_h = logaddexp(log_h + lf, lv).

#define BB 4
#define SS 8192
#define DD 1024
#define MM 32768   // B*S
#define KK 1024    // D
#define NN 3072    // 3*D
#define CHUNKS 64
#define CLEN 128   // SS / CHUNKS
#define NCH 4096   // B*D channels

typedef __bf16 bf16;
typedef __bf16 bf16x2 __attribute__((ext_vector_type(2)));
typedef __bf16 bf16x4 __attribute__((ext_vector_type(4)));
typedef __bf16 bf16x8 __attribute__((ext_vector_type(8)));
typedef float f32x4 __attribute__((ext_vector_type(4)));

// ---- async global->LDS, 16B per lane (wave-uniform LDS base + lane*16) ----
__device__ __forceinline__ void gload16(const bf16* g, bf16* l) {
  __builtin_amdgcn_global_load_lds(
      (const __attribute__((address_space(1))) unsigned int*)(const void*)g,
      (__attribute__((address_space(3))) unsigned int*)(void*)l,
      16, 0, 0);
}

// ---- scalar math helpers ----
__device__ __forceinline__ float sp(float x) {  // softplus, stable
  return fmaxf(x, 0.f) + __logf(1.f + __expf(-fabsf(x)));
}
__device__ __forceinline__ void gates(float h, float f, float i,
                                      float& lf, float& lv) {
  float d = sp(-f) - sp(-i);
  float spd = sp(d);
  lf = -spd;            // -softplus(diff)
  float li = d - spd;   // -softplus(-diff)
  float lg = (h >= 0.f) ? __logf(h + 0.5f) : -sp(-h);
  lv = li + lg;
}
__device__ __forceinline__ float laddexp(float a, float b) {
  float m = fmaxf(a, b);
  return m + __logf(1.f + __expf(fminf(a, b) - m));
}

// ---- convert x fp32 -> bf16 (vectorized) ----
__global__ __launch_bounds__(256) void k_cvt_x(const float4* __restrict__ x,
                                               bf16x4* __restrict__ xb) {
  int i = blockIdx.x * 256 + threadIdx.x;
  float4 v = x[i];
  bf16x4 o;
  o[0] = (bf16)v.x; o[1] = (bf16)v.y; o[2] = (bf16)v.z; o[3] = (bf16)v.w;
  xb[i] = o;
}

// ---- convert + transpose W [K,N] fp32 -> Wt [N,K] bf16 (LDS 32x32 tile) ----
__global__ __launch_bounds__(256) void k_cvt_wt(const float* __restrict__ W,
                                                bf16* __restrict__ Wt) {
  __shared__ float tile[32][33];
  int n0 = blockIdx.x * 32, k0 = blockIdx.y * 32;
  int tx = threadIdx.x, ty = threadIdx.y;  // (32, 8)
#pragma unroll
  for (int i = 0; i < 32; i += 8)
    tile[ty + i][tx] = W[(size_t)(k0 + ty + i) * NN + n0 + tx];
  __syncthreads();
#pragma unroll
  for (int i = 0; i < 32; i += 8)
    Wt[(size_t)(n0 + ty + i) * KK + k0 + tx] = (bf16)tile[tx][ty + i];
}

// ---- bf16 GEMM, C[m][n] = sum_k A[m][k]*Bt[n][k]; 128x128 tile, BK=32 ------
// m97 structure + LDS-transposed coalesced bf16 epilogue.
__global__ __launch_bounds__(256) void k_gemm(const bf16* __restrict__ A,
                                              const bf16* __restrict__ Bt,
                                              bf16* __restrict__ C) {
  // smem serves two roles: K-loop staging (As 4096 + Bs 4096 elems) and the
  // epilogue 64x(128+4) transpose tile (8448 elems). Max = 8448 elems.
  __shared__ bf16 smem[64 * 132];
  bf16* As = smem;           // 128*32
  bf16* Bs = smem + 4096;    // 128*32
  const int tid = threadIdx.x;
  const int nBase = blockIdx.x * 128;
  const int mBase = blockIdx.y * 128;
  const int lane = tid & 63;
  const int w = tid >> 6;
  const int wm = (w >> 1) * 64, wn = (w & 1) * 64;
  const int col16 = lane & 15;       // m (A) / n (B) / col (C)
  const int kq = (lane >> 4) * 8;    // k quad offset
  const int r0 = tid >> 2;           // staging row 0..63
  const int cc = (tid & 3) * 8;      // staging col (elems)
  const bf16* ga0 = A + (size_t)(mBase + r0) * KK + cc;
  const bf16* ga1 = A + (size_t)(mBase + 64 + r0) * KK + cc;
  const bf16* gb0 = Bt + (size_t)(nBase + r0) * KK + cc;
  const bf16* gb1 = Bt + (size_t)(nBase + 64 + r0) * KK + cc;
  bf16* la = As + tid * 8;  // per-wave-contiguous: byte = w*1024 + lane*16
  bf16* lb = Bs + tid * 8;

  f32x4 acc[4][4];
#pragma unroll
  for (int mi = 0; mi < 4; ++mi)
#pragma unroll
    for (int ni = 0; ni < 4; ++ni)
      acc[mi][ni] = (f32x4){0.f, 0.f, 0.f, 0.f};

  for (int k0 = 0; k0 < KK; k0 += 32) {
    gload16(ga0 + k0, la);
    gload16(ga1 + k0, la + 2048);
    gload16(gb0 + k0, lb);
    gload16(gb1 + k0, lb + 2048);
    __syncthreads();  // drains vmcnt (async LDS writes) + barrier
    bf16x8 afr[4], bfr[4];
#pragma unroll
    for (int mi = 0; mi < 4; ++mi)
      afr[mi] = *(const bf16x8*)(As + (wm + mi * 16 + col16) * 32 + kq);
#pragma unroll
    for (int ni = 0; ni < 4; ++ni)
      bfr[ni] = *(const bf16x8*)(Bs + (wn + ni * 16 + col16) * 32 + kq);
#pragma unroll
    for (int mi = 0; mi < 4; ++mi)
#pragma unroll
      for (int ni = 0; ni < 4; ++ni)
        acc[mi][ni] = __builtin_amdgcn_mfma_f32_16x16x32_bf16(
            afr[mi], bfr[ni], acc[mi][ni], 0, 0, 0);
    __syncthreads();  // reads done before next stage overwrites
  }

  // Epilogue: C/D layout col=lane&15, row=(lane>>4)*4+reg [m89-verified].
  // Round-trip through LDS (row pitch 132 bf16 -> conflict-free) to emit
  // coalesced 16B bf16x8 stores.
  const int rowq = (lane >> 4) * 4;
#pragma unroll
  for (int ph = 0; ph < 2; ++ph) {
    if (wm == ph * 64) {
#pragma unroll
      for (int mi = 0; mi < 4; ++mi)
#pragma unroll
        for (int ni = 0; ni < 4; ++ni)
#pragma unroll
          for (int r = 0; r < 4; ++r)
            smem[(mi * 16 + rowq + r) * 132 + wn + ni * 16 + col16] =
                (bf16)acc[mi][ni][r];
    }
    __syncthreads();
#pragma unroll
    for (int pass = 0; pass < 4; ++pass) {
      int row = pass * 16 + (tid >> 4);
      int col = (tid & 15) * 8;
      bf16x8 v = *(const bf16x8*)(smem + row * 132 + col);
      *(bf16x8*)(C + (size_t)(mBase + ph * 64 + row) * NN + nBase + col) = v;
    }
    __syncthreads();
  }
}

// ---- scan phase 1: per (channel-pair, chunk) aggregate ----------------------
__global__ __launch_bounds__(256) void k_scan1(const bf16* __restrict__ hW,
                                               float2* __restrict__ agg) {
  const int d0 = (blockIdx.x * 256 + threadIdx.x) * 2;
  const int b = blockIdx.y, c = blockIdx.z;
  const bf16* p = hW + (size_t)(b * SS + c * CLEN) * NN + d0;
  float A0 = 0.f, V0 = -1e30f, A1 = 0.f, V1 = -1e30f;
  for (int j = 0; j < CLEN; ++j) {
    bf16x2 hh = *(const bf16x2*)(p);
    bf16x2 ff = *(const bf16x2*)(p + DD);
    bf16x2 ii = *(const bf16x2*)(p + 2 * DD);
    float lf, lv;
    gates((float)hh[0], (float)ff[0], (float)ii[0], lf, lv);
    A0 += lf; V0 = laddexp(V0 + lf, lv);
    gates((float)hh[1], (float)ff[1], (float)ii[1], lf, lv);
    A1 += lf; V1 = laddexp(V1 + lf, lv);
    p += NN;
  }
  float2* a = agg + (size_t)c * NCH + b * DD + d0;
  a[0] = make_float2(A0, V0);
  a[1] = make_float2(A1, V1);
}

// ---- scan phase 2: exclusive prefix over chunks, one thread per channel ----
__global__ __launch_bounds__(256) void k_scan2(const float2* __restrict__ agg,
                                               float2* __restrict__ pre) {
  const int ch = blockIdx.x * 256 + threadIdx.x;
  float A = 0.f, V = -1e30f;
  for (int c = 0; c < CHUNKS; ++c) {
    pre[(size_t)c * NCH + ch] = make_float2(A, V);
    float2 ag = agg[(size_t)c * NCH + ch];
    V = laddexp(ag.y, ag.x + V);
    A += ag.x;
  }
}

// ---- scan phase 3: re-run chunk with prefix init, write exp(log_h) ---------
__global__ __launch_bounds__(256) void k_scan3(const bf16* __restrict__ hW,
                                               const float2* __restrict__ pre,
                                               float* __restrict__ out) {
  const int d0 = (blockIdx.x * 256 + threadIdx.x) * 2;
  const int b = blockIdx.y, c = blockIdx.z;
  const bf16* p = hW + (size_t)(b * SS + c * CLEN) * NN + d0;
  float* o = out + (size_t)(b * SS + c * CLEN) * DD + d0;
  const float2* pr = pre + (size_t)c * NCH + b * DD + d0;
  float V0 = pr[0].y, V1 = pr[1].y;
  for (int j = 0; j < CLEN; ++j) {
    bf16x2 hh = *(const bf16x2*)(p);
    bf16x2 ff = *(const bf16x2*)(p + DD);
    bf16x2 ii = *(const bf16x2*)(p + 2 * DD);
    float lf, lv;
    gates((float)hh[0], (float)ff[0], (float)ii[0], lf, lv);
    V0 = laddexp(V0 + lf, lv);
    gates((float)hh[1], (float)ff[1], (float)ii[1], lf, lv);
    V1 = laddexp(V1 + lf, lv);
    *(float2*)o = make_float2(__expf(V0), __expf(V1));
    p += NN;
    o += DD;
  }
}

extern "C" void kernel_launch(void* const* d_in, const int* in_sizes, int n_in,
                              void* d_out, int out_size, void* d_ws,
                              size_t ws_size, hipStream_t stream) {
  const float* x = (const float*)d_in[0];
  const float* W = (const float*)d_in[1];
  float* out = (float*)d_out;
  char* ws = (char*)d_ws;

  // workspace layout (all bf16 hW): 6 MB Wt + 64 MB xb + 192 MB hW + 4 MB agg
  const size_t wtB = (size_t)NN * KK * 2;   //  6,291,456
  const size_t xbB = (size_t)MM * KK * 2;   // 67,108,864
  const size_t hwB = (size_t)MM * NN * 2;   // 201,326,592
  const size_t aggB = (size_t)CHUNKS * NCH * sizeof(float2);  // 2 MiB
  bf16* Wt = (bf16*)ws;
  bf16* xb = (bf16*)(ws + wtB);
  bf16* hW = (bf16*)(ws + wtB + xbB);
  float2* agg = (float2*)(ws + wtB + xbB + hwB);
  float2* pre = (float2*)(ws + wtB + xbB + hwB + aggB);

  k_cvt_wt<<<dim3(NN / 32, KK / 32), dim3(32, 8), 0, stream>>>(W, Wt);
  k_cvt_x<<<dim3(MM * KK / 4 / 256), dim3(256), 0, stream>>>((const float4*)x,
                                                             (bf16x4*)xb);
  k_gemm<<<dim3(NN / 128, MM / 128), 256, 0, stream>>>(xb, Wt, hW);
  k_scan1<<<dim3(DD / 512, BB, CHUNKS), 256, 0, stream>>>(hW, agg);
  k_scan2<<<dim3(NCH / 256), 256, 0, stream>>>(agg, pre);
  k_scan3<<<dim3(DD / 512, BB, CHUNKS), 256, 0, stream>>>(hW, pre, out);
}

// Round 3
// 685.099 us; speedup vs baseline: 1.2337x; 1.0869x over previous
//
#include <hip/hip_runtime.h>
#include <hip/hip_bf16.h>
#include <cstdint>
#include <cstddef>

// minLSTM: out = exp(heinsen_scan(log_f, log_i + log_g(h))), [h,f,i] = x @ W
// B=4 S=8192 D=1024. GEMM bf16 MFMA (fp32 accum) -> bf16 hW; fp32 log-space
// chunked scan with recurrence log_h = logaddexp(log_h + lf, lv).
// R3: CHUNKS 64->256 (full occupancy in scans) + software-pipelined scan loads.

#define BB 4
#define SS 8192
#define DD 1024
#define MM 32768   // B*S
#define KK 1024    // D
#define NN 3072    // 3*D
#define CHUNKS 256
#define CLEN 32    // SS / CHUNKS
#define NCH 4096   // B*D channels

typedef __bf16 bf16;
typedef __bf16 bf16x2 __attribute__((ext_vector_type(2)));
typedef __bf16 bf16x4 __attribute__((ext_vector_type(4)));
typedef __bf16 bf16x8 __attribute__((ext_vector_type(8)));
typedef float f32x4 __attribute__((ext_vector_type(4)));

// ---- async global->LDS, 16B per lane (wave-uniform LDS base + lane*16) ----
__device__ __forceinline__ void gload16(const bf16* g, bf16* l) {
  __builtin_amdgcn_global_load_lds(
      (const __attribute__((address_space(1))) unsigned int*)(const void*)g,
      (__attribute__((address_space(3))) unsigned int*)(void*)l,
      16, 0, 0);
}

// ---- scalar math helpers ----
__device__ __forceinline__ float sp(float x) {  // softplus, stable
  return fmaxf(x, 0.f) + __logf(1.f + __expf(-fabsf(x)));
}
__device__ __forceinline__ void gates(float h, float f, float i,
                                      float& lf, float& lv) {
  float d = sp(-f) - sp(-i);
  float spd = sp(d);
  lf = -spd;            // -softplus(diff)
  float li = d - spd;   // -softplus(-diff)
  float lg = (h >= 0.f) ? __logf(h + 0.5f) : -sp(-h);
  lv = li + lg;
}
__device__ __forceinline__ float laddexp(float a, float b) {
  float m = fmaxf(a, b);
  return m + __logf(1.f + __expf(fminf(a, b) - m));
}

// ---- convert x fp32 -> bf16 (vectorized) ----
__global__ __launch_bounds__(256) void k_cvt_x(const float4* __restrict__ x,
                                               bf16x4* __restrict__ xb) {
  int i = blockIdx.x * 256 + threadIdx.x;
  float4 v = x[i];
  bf16x4 o;
  o[0] = (bf16)v.x; o[1] = (bf16)v.y; o[2] = (bf16)v.z; o[3] = (bf16)v.w;
  xb[i] = o;
}

// ---- convert + transpose W [K,N] fp32 -> Wt [N,K] bf16 (LDS 32x32 tile) ----
__global__ __launch_bounds__(256) void k_cvt_wt(const float* __restrict__ W,
                                                bf16* __restrict__ Wt) {
  __shared__ float tile[32][33];
  int n0 = blockIdx.x * 32, k0 = blockIdx.y * 32;
  int tx = threadIdx.x, ty = threadIdx.y;  // (32, 8)
#pragma unroll
  for (int i = 0; i < 32; i += 8)
    tile[ty + i][tx] = W[(size_t)(k0 + ty + i) * NN + n0 + tx];
  __syncthreads();
#pragma unroll
  for (int i = 0; i < 32; i += 8)
    Wt[(size_t)(n0 + ty + i) * KK + k0 + tx] = (bf16)tile[tx][ty + i];
}

// ---- bf16 GEMM, C[m][n] = sum_k A[m][k]*Bt[n][k]; 128x128 tile, BK=32 ------
// m97 structure + LDS-transposed coalesced bf16 epilogue. (unchanged from R2)
__global__ __launch_bounds__(256) void k_gemm(const bf16* __restrict__ A,
                                              const bf16* __restrict__ Bt,
                                              bf16* __restrict__ C) {
  __shared__ bf16 smem[64 * 132];
  bf16* As = smem;           // 128*32
  bf16* Bs = smem + 4096;    // 128*32
  const int tid = threadIdx.x;
  const int nBase = blockIdx.x * 128;
  const int mBase = blockIdx.y * 128;
  const int lane = tid & 63;
  const int w = tid >> 6;
  const int wm = (w >> 1) * 64, wn = (w & 1) * 64;
  const int col16 = lane & 15;       // m (A) / n (B) / col (C)
  const int kq = (lane >> 4) * 8;    // k quad offset
  const int r0 = tid >> 2;           // staging row 0..63
  const int cc = (tid & 3) * 8;      // staging col (elems)
  const bf16* ga0 = A + (size_t)(mBase + r0) * KK + cc;
  const bf16* ga1 = A + (size_t)(mBase + 64 + r0) * KK + cc;
  const bf16* gb0 = Bt + (size_t)(nBase + r0) * KK + cc;
  const bf16* gb1 = Bt + (size_t)(nBase + 64 + r0) * KK + cc;
  bf16* la = As + tid * 8;  // per-wave-contiguous: byte = w*1024 + lane*16
  bf16* lb = Bs + tid * 8;

  f32x4 acc[4][4];
#pragma unroll
  for (int mi = 0; mi < 4; ++mi)
#pragma unroll
    for (int ni = 0; ni < 4; ++ni)
      acc[mi][ni] = (f32x4){0.f, 0.f, 0.f, 0.f};

  for (int k0 = 0; k0 < KK; k0 += 32) {
    gload16(ga0 + k0, la);
    gload16(ga1 + k0, la + 2048);
    gload16(gb0 + k0, lb);
    gload16(gb1 + k0, lb + 2048);
    __syncthreads();  // drains vmcnt (async LDS writes) + barrier
    bf16x8 afr[4], bfr[4];
#pragma unroll
    for (int mi = 0; mi < 4; ++mi)
      afr[mi] = *(const bf16x8*)(As + (wm + mi * 16 + col16) * 32 + kq);
#pragma unroll
    for (int ni = 0; ni < 4; ++ni)
      bfr[ni] = *(const bf16x8*)(Bs + (wn + ni * 16 + col16) * 32 + kq);
#pragma unroll
    for (int mi = 0; mi < 4; ++mi)
#pragma unroll
      for (int ni = 0; ni < 4; ++ni)
        acc[mi][ni] = __builtin_amdgcn_mfma_f32_16x16x32_bf16(
            afr[mi], bfr[ni], acc[mi][ni], 0, 0, 0);
    __syncthreads();  // reads done before next stage overwrites
  }

  // Epilogue: C/D layout col=lane&15, row=(lane>>4)*4+reg [m89-verified].
  const int rowq = (lane >> 4) * 4;
#pragma unroll
  for (int ph = 0; ph < 2; ++ph) {
    if (wm == ph * 64) {
#pragma unroll
      for (int mi = 0; mi < 4; ++mi)
#pragma unroll
        for (int ni = 0; ni < 4; ++ni)
#pragma unroll
          for (int r = 0; r < 4; ++r)
            smem[(mi * 16 + rowq + r) * 132 + wn + ni * 16 + col16] =
                (bf16)acc[mi][ni][r];
    }
    __syncthreads();
#pragma unroll
    for (int pass = 0; pass < 4; ++pass) {
      int row = pass * 16 + (tid >> 4);
      int col = (tid & 15) * 8;
      bf16x8 v = *(const bf16x8*)(smem + row * 132 + col);
      *(bf16x8*)(C + (size_t)(mBase + ph * 64 + row) * NN + nBase + col) = v;
    }
    __syncthreads();
  }
}

// ---- scan phase 1: per (channel-pair, chunk) aggregate, pipelined ----------
__global__ __launch_bounds__(256, 6) void k_scan1(const bf16* __restrict__ hW,
                                                  float2* __restrict__ agg) {
  const int d0 = (blockIdx.x * 256 + threadIdx.x) * 2;
  const int b = blockIdx.y, c = blockIdx.z;
  const bf16* p = hW + (size_t)(b * SS + c * CLEN) * NN + d0;
  float A0 = 0.f, V0 = -1e30f, A1 = 0.f, V1 = -1e30f;
  bf16x2 hh = *(const bf16x2*)(p);
  bf16x2 ff = *(const bf16x2*)(p + DD);
  bf16x2 ii = *(const bf16x2*)(p + 2 * DD);
#pragma unroll 4
  for (int j = 0; j < CLEN - 1; ++j) {
    p += NN;
    bf16x2 hn = *(const bf16x2*)(p);
    bf16x2 fn = *(const bf16x2*)(p + DD);
    bf16x2 in2 = *(const bf16x2*)(p + 2 * DD);
    float lf, lv;
    gates((float)hh[0], (float)ff[0], (float)ii[0], lf, lv);
    A0 += lf; V0 = laddexp(V0 + lf, lv);
    gates((float)hh[1], (float)ff[1], (float)ii[1], lf, lv);
    A1 += lf; V1 = laddexp(V1 + lf, lv);
    hh = hn; ff = fn; ii = in2;
  }
  float lf, lv;
  gates((float)hh[0], (float)ff[0], (float)ii[0], lf, lv);
  A0 += lf; V0 = laddexp(V0 + lf, lv);
  gates((float)hh[1], (float)ff[1], (float)ii[1], lf, lv);
  A1 += lf; V1 = laddexp(V1 + lf, lv);
  float2* a = agg + (size_t)c * NCH + b * DD + d0;
  a[0] = make_float2(A0, V0);
  a[1] = make_float2(A1, V1);
}

// ---- scan phase 2: exclusive prefix over chunks, one thread per channel ----
__global__ __launch_bounds__(256) void k_scan2(const float2* __restrict__ agg,
                                               float2* __restrict__ pre) {
  const int ch = blockIdx.x * 256 + threadIdx.x;
  float A = 0.f, V = -1e30f;
  for (int c = 0; c < CHUNKS; ++c) {
    pre[(size_t)c * NCH + ch] = make_float2(A, V);
    float2 ag = agg[(size_t)c * NCH + ch];
    V = laddexp(ag.y, ag.x + V);
    A += ag.x;
  }
}

// ---- scan phase 3: re-run chunk with prefix init, write exp(log_h) ---------
__global__ __launch_bounds__(256, 6) void k_scan3(const bf16* __restrict__ hW,
                                                  const float2* __restrict__ pre,
                                                  float* __restrict__ out) {
  const int d0 = (blockIdx.x * 256 + threadIdx.x) * 2;
  const int b = blockIdx.y, c = blockIdx.z;
  const bf16* p = hW + (size_t)(b * SS + c * CLEN) * NN + d0;
  float* o = out + (size_t)(b * SS + c * CLEN) * DD + d0;
  const float2* pr = pre + (size_t)c * NCH + b * DD + d0;
  float V0 = pr[0].y, V1 = pr[1].y;
  bf16x2 hh = *(const bf16x2*)(p);
  bf16x2 ff = *(const bf16x2*)(p + DD);
  bf16x2 ii = *(const bf16x2*)(p + 2 * DD);
#pragma unroll 4
  for (int j = 0; j < CLEN - 1; ++j) {
    p += NN;
    bf16x2 hn = *(const bf16x2*)(p);
    bf16x2 fn = *(const bf16x2*)(p + DD);
    bf16x2 in2 = *(const bf16x2*)(p + 2 * DD);
    float lf, lv;
    gates((float)hh[0], (float)ff[0], (float)ii[0], lf, lv);
    V0 = laddexp(V0 + lf, lv);
    gates((float)hh[1], (float)ff[1], (float)ii[1], lf, lv);
    V1 = laddexp(V1 + lf, lv);
    *(float2*)o = make_float2(__expf(V0), __expf(V1));
    o += DD;
    hh = hn; ff = fn; ii = in2;
  }
  float lf, lv;
  gates((float)hh[0], (float)ff[0], (float)ii[0], lf, lv);
  V0 = laddexp(V0 + lf, lv);
  gates((float)hh[1], (float)ff[1], (float)ii[1], lf, lv);
  V1 = laddexp(V1 + lf, lv);
  *(float2*)o = make_float2(__expf(V0), __expf(V1));
}

extern "C" void kernel_launch(void* const* d_in, const int* in_sizes, int n_in,
                              void* d_out, int out_size, void* d_ws,
                              size_t ws_size, hipStream_t stream) {
  const float* x = (const float*)d_in[0];
  const float* W = (const float*)d_in[1];
  float* out = (float*)d_out;
  char* ws = (char*)d_ws;

  // workspace layout: [Wt 6MB][xb 64MB][hW 192MB]; agg/pre (8MB each) overlay
  // the xb region, which is dead after the GEMM completes.
  const size_t wtB = (size_t)NN * KK * 2;   //  6,291,456
  const size_t xbB = (size_t)MM * KK * 2;   // 67,108,864
  const size_t aggB = (size_t)CHUNKS * NCH * sizeof(float2);  // 8 MiB
  bf16* Wt = (bf16*)ws;
  bf16* xb = (bf16*)(ws + wtB);
  bf16* hW = (bf16*)(ws + wtB + xbB);
  float2* agg = (float2*)(ws + wtB);          // overlays xb (dead post-GEMM)
  float2* pre = (float2*)(ws + wtB + aggB);

  k_cvt_wt<<<dim3(NN / 32, KK / 32), dim3(32, 8), 0, stream>>>(W, Wt);
  k_cvt_x<<<dim3(MM * KK / 4 / 256), dim3(256), 0, stream>>>((const float4*)x,
                                                             (bf16x4*)xb);
  k_gemm<<<dim3(NN / 128, MM / 128), 256, 0, stream>>>(xb, Wt, hW);
  k_scan1<<<dim3(DD / 512, BB, CHUNKS), 256, 0, stream>>>(hW, agg);
  k_scan2<<<dim3(NCH / 256), 256, 0, stream>>>(agg, pre);
  k_scan3<<<dim3(DD / 512, BB, CHUNKS), 256, 0, stream>>>(hW, pre, out);
}

// Round 4
// 643.965 us; speedup vs baseline: 1.3125x; 1.0639x over previous
//
#include <hip/hip_runtime.h>
#include <hip/hip_bf16.h>
#include <cstdint>
#include <cstddef>

// minLSTM: out = exp(heinsen_scan(log_f, log_i + log_g(h))), [h,f,i] = x @ W
// B=4 S=8192 D=1024. GEMM bf16 MFMA (fp32 accum) -> bf16 hW; fp32 log-space
// chunked scan with recurrence log_h = logaddexp(log_h + lf, lv).
// R4: wave-parallel shfl scan for phase 2 (was 256-long serial chain on 16
// blocks); agg/pre transposed to [channel][chunk] for coalesced wave access.

#define BB 4
#define SS 8192
#define DD 1024
#define MM 32768   // B*S
#define KK 1024    // D
#define NN 3072    // 3*D
#define CHUNKS 256
#define CLEN 32    // SS / CHUNKS
#define NCH 4096   // B*D channels

typedef __bf16 bf16;
typedef __bf16 bf16x2 __attribute__((ext_vector_type(2)));
typedef __bf16 bf16x4 __attribute__((ext_vector_type(4)));
typedef __bf16 bf16x8 __attribute__((ext_vector_type(8)));
typedef float f32x4 __attribute__((ext_vector_type(4)));

// ---- async global->LDS, 16B per lane (wave-uniform LDS base + lane*16) ----
__device__ __forceinline__ void gload16(const bf16* g, bf16* l) {
  __builtin_amdgcn_global_load_lds(
      (const __attribute__((address_space(1))) unsigned int*)(const void*)g,
      (__attribute__((address_space(3))) unsigned int*)(void*)l,
      16, 0, 0);
}

// ---- scalar math helpers ----
__device__ __forceinline__ float sp(float x) {  // softplus, stable
  return fmaxf(x, 0.f) + __logf(1.f + __expf(-fabsf(x)));
}
__device__ __forceinline__ void gates(float h, float f, float i,
                                      float& lf, float& lv) {
  float d = sp(-f) - sp(-i);
  float spd = sp(d);
  lf = -spd;            // -softplus(diff)
  float li = d - spd;   // -softplus(-diff)
  float lg = (h >= 0.f) ? __logf(h + 0.5f) : -sp(-h);
  lv = li + lg;
}
__device__ __forceinline__ float laddexp(float a, float b) {
  float m = fmaxf(a, b);
  return m + __logf(1.f + __expf(fminf(a, b) - m));
}
// combine running state (A,V) with chunk aggregate (Ac,Vc), chunk on the right
__device__ __forceinline__ void comb(float& A, float& V, float Ac, float Vc) {
  V = laddexp(V + Ac, Vc);
  A += Ac;
}

// ---- convert x fp32 -> bf16 (vectorized) ----
__global__ __launch_bounds__(256) void k_cvt_x(const float4* __restrict__ x,
                                               bf16x4* __restrict__ xb) {
  int i = blockIdx.x * 256 + threadIdx.x;
  float4 v = x[i];
  bf16x4 o;
  o[0] = (bf16)v.x; o[1] = (bf16)v.y; o[2] = (bf16)v.z; o[3] = (bf16)v.w;
  xb[i] = o;
}

// ---- convert + transpose W [K,N] fp32 -> Wt [N,K] bf16 (LDS 32x32 tile) ----
__global__ __launch_bounds__(256) void k_cvt_wt(const float* __restrict__ W,
                                                bf16* __restrict__ Wt) {
  __shared__ float tile[32][33];
  int n0 = blockIdx.x * 32, k0 = blockIdx.y * 32;
  int tx = threadIdx.x, ty = threadIdx.y;  // (32, 8)
#pragma unroll
  for (int i = 0; i < 32; i += 8)
    tile[ty + i][tx] = W[(size_t)(k0 + ty + i) * NN + n0 + tx];
  __syncthreads();
#pragma unroll
  for (int i = 0; i < 32; i += 8)
    Wt[(size_t)(n0 + ty + i) * KK + k0 + tx] = (bf16)tile[tx][ty + i];
}

// ---- bf16 GEMM, C[m][n] = sum_k A[m][k]*Bt[n][k]; 128x128 tile, BK=32 ------
// m97 structure + LDS-transposed coalesced bf16 epilogue. (unchanged)
__global__ __launch_bounds__(256) void k_gemm(const bf16* __restrict__ A,
                                              const bf16* __restrict__ Bt,
                                              bf16* __restrict__ C) {
  __shared__ bf16 smem[64 * 132];
  bf16* As = smem;           // 128*32
  bf16* Bs = smem + 4096;    // 128*32
  const int tid = threadIdx.x;
  const int nBase = blockIdx.x * 128;
  const int mBase = blockIdx.y * 128;
  const int lane = tid & 63;
  const int w = tid >> 6;
  const int wm = (w >> 1) * 64, wn = (w & 1) * 64;
  const int col16 = lane & 15;       // m (A) / n (B) / col (C)
  const int kq = (lane >> 4) * 8;    // k quad offset
  const int r0 = tid >> 2;           // staging row 0..63
  const int cc = (tid & 3) * 8;      // staging col (elems)
  const bf16* ga0 = A + (size_t)(mBase + r0) * KK + cc;
  const bf16* ga1 = A + (size_t)(mBase + 64 + r0) * KK + cc;
  const bf16* gb0 = Bt + (size_t)(nBase + r0) * KK + cc;
  const bf16* gb1 = Bt + (size_t)(nBase + 64 + r0) * KK + cc;
  bf16* la = As + tid * 8;  // per-wave-contiguous: byte = w*1024 + lane*16
  bf16* lb = Bs + tid * 8;

  f32x4 acc[4][4];
#pragma unroll
  for (int mi = 0; mi < 4; ++mi)
#pragma unroll
    for (int ni = 0; ni < 4; ++ni)
      acc[mi][ni] = (f32x4){0.f, 0.f, 0.f, 0.f};

  for (int k0 = 0; k0 < KK; k0 += 32) {
    gload16(ga0 + k0, la);
    gload16(ga1 + k0, la + 2048);
    gload16(gb0 + k0, lb);
    gload16(gb1 + k0, lb + 2048);
    __syncthreads();  // drains vmcnt (async LDS writes) + barrier
    bf16x8 afr[4], bfr[4];
#pragma unroll
    for (int mi = 0; mi < 4; ++mi)
      afr[mi] = *(const bf16x8*)(As + (wm + mi * 16 + col16) * 32 + kq);
#pragma unroll
    for (int ni = 0; ni < 4; ++ni)
      bfr[ni] = *(const bf16x8*)(Bs + (wn + ni * 16 + col16) * 32 + kq);
#pragma unroll
    for (int mi = 0; mi < 4; ++mi)
#pragma unroll
      for (int ni = 0; ni < 4; ++ni)
        acc[mi][ni] = __builtin_amdgcn_mfma_f32_16x16x32_bf16(
            afr[mi], bfr[ni], acc[mi][ni], 0, 0, 0);
    __syncthreads();  // reads done before next stage overwrites
  }

  // Epilogue: C/D layout col=lane&15, row=(lane>>4)*4+reg [m89-verified].
  const int rowq = (lane >> 4) * 4;
#pragma unroll
  for (int ph = 0; ph < 2; ++ph) {
    if (wm == ph * 64) {
#pragma unroll
      for (int mi = 0; mi < 4; ++mi)
#pragma unroll
        for (int ni = 0; ni < 4; ++ni)
#pragma unroll
          for (int r = 0; r < 4; ++r)
            smem[(mi * 16 + rowq + r) * 132 + wn + ni * 16 + col16] =
                (bf16)acc[mi][ni][r];
    }
    __syncthreads();
#pragma unroll
    for (int pass = 0; pass < 4; ++pass) {
      int row = pass * 16 + (tid >> 4);
      int col = (tid & 15) * 8;
      bf16x8 v = *(const bf16x8*)(smem + row * 132 + col);
      *(bf16x8*)(C + (size_t)(mBase + ph * 64 + row) * NN + nBase + col) = v;
    }
    __syncthreads();
  }
}

// ---- scan phase 1: per (channel-pair, chunk) aggregate, pipelined ----------
// agg layout: [channel][chunk] (channel = b*DD + d)
__global__ __launch_bounds__(256, 6) void k_scan1(const bf16* __restrict__ hW,
                                                  float2* __restrict__ agg) {
  const int d0 = (blockIdx.x * 256 + threadIdx.x) * 2;
  const int b = blockIdx.y, c = blockIdx.z;
  const bf16* p = hW + (size_t)(b * SS + c * CLEN) * NN + d0;
  float A0 = 0.f, V0 = -1e30f, A1 = 0.f, V1 = -1e30f;
  bf16x2 hh = *(const bf16x2*)(p);
  bf16x2 ff = *(const bf16x2*)(p + DD);
  bf16x2 ii = *(const bf16x2*)(p + 2 * DD);
#pragma unroll 4
  for (int j = 0; j < CLEN - 1; ++j) {
    p += NN;
    bf16x2 hn = *(const bf16x2*)(p);
    bf16x2 fn = *(const bf16x2*)(p + DD);
    bf16x2 in2 = *(const bf16x2*)(p + 2 * DD);
    float lf, lv;
    gates((float)hh[0], (float)ff[0], (float)ii[0], lf, lv);
    A0 += lf; V0 = laddexp(V0 + lf, lv);
    gates((float)hh[1], (float)ff[1], (float)ii[1], lf, lv);
    A1 += lf; V1 = laddexp(V1 + lf, lv);
    hh = hn; ff = fn; ii = in2;
  }
  float lf, lv;
  gates((float)hh[0], (float)ff[0], (float)ii[0], lf, lv);
  A0 += lf; V0 = laddexp(V0 + lf, lv);
  gates((float)hh[1], (float)ff[1], (float)ii[1], lf, lv);
  A1 += lf; V1 = laddexp(V1 + lf, lv);
  const size_t ch = (size_t)b * DD + d0;
  agg[ch * CHUNKS + c] = make_float2(A0, V0);
  agg[(ch + 1) * CHUNKS + c] = make_float2(A1, V1);
}

// ---- scan phase 2: wave-parallel exclusive scan over chunks ----------------
// One wave per channel; lane holds 4 chunk aggregates; shfl tree scan.
__global__ __launch_bounds__(256) void k_scan2(const float2* __restrict__ agg,
                                               float2* __restrict__ pre) {
  const int ch = blockIdx.x * 4 + (threadIdx.x >> 6);
  const int lane = threadIdx.x & 63;
  const float4* src = (const float4*)(agg + (size_t)ch * CHUNKS);
  float4 v0 = src[lane * 2];      // chunks 4*lane, 4*lane+1
  float4 v1 = src[lane * 2 + 1];  // chunks 4*lane+2, 4*lane+3
  // lane-local fold
  float A = v0.x, V = v0.y;
  comb(A, V, v0.z, v0.w);
  comb(A, V, v1.x, v1.y);
  comb(A, V, v1.z, v1.w);
  // inclusive wave scan of lane aggregates
#pragma unroll
  for (int off = 1; off < 64; off <<= 1) {
    float Ao = __shfl_up(A, off);
    float Vo = __shfl_up(V, off);
    if (lane >= off) {
      // combine(left=other, right=self)
      V = laddexp(Vo + A, V);
      A = Ao + A;
    }
  }
  // exclusive lane prefix
  float exA = __shfl_up(A, 1);
  float exV = __shfl_up(V, 1);
  if (lane == 0) { exA = 0.f; exV = -1e30f; }
  // produce exclusive per-chunk prefixes
  float4 o0, o1;
  o0.x = exA; o0.y = exV;
  comb(exA, exV, v0.x, v0.y);
  o0.z = exA; o0.w = exV;
  comb(exA, exV, v0.z, v0.w);
  o1.x = exA; o1.y = exV;
  comb(exA, exV, v1.x, v1.y);
  o1.z = exA; o1.w = exV;
  float4* dst = (float4*)(pre + (size_t)ch * CHUNKS);
  dst[lane * 2] = o0;
  dst[lane * 2 + 1] = o1;
}

// ---- scan phase 3: re-run chunk with prefix init, write exp(log_h) ---------
__global__ __launch_bounds__(256, 6) void k_scan3(const bf16* __restrict__ hW,
                                                  const float2* __restrict__ pre,
                                                  float* __restrict__ out) {
  const int d0 = (blockIdx.x * 256 + threadIdx.x) * 2;
  const int b = blockIdx.y, c = blockIdx.z;
  const bf16* p = hW + (size_t)(b * SS + c * CLEN) * NN + d0;
  float* o = out + (size_t)(b * SS + c * CLEN) * DD + d0;
  const size_t ch = (size_t)b * DD + d0;
  float V0 = pre[ch * CHUNKS + c].y;
  float V1 = pre[(ch + 1) * CHUNKS + c].y;
  bf16x2 hh = *(const bf16x2*)(p);
  bf16x2 ff = *(const bf16x2*)(p + DD);
  bf16x2 ii = *(const bf16x2*)(p + 2 * DD);
#pragma unroll 4
  for (int j = 0; j < CLEN - 1; ++j) {
    p += NN;
    bf16x2 hn = *(const bf16x2*)(p);
    bf16x2 fn = *(const bf16x2*)(p + DD);
    bf16x2 in2 = *(const bf16x2*)(p + 2 * DD);
    float lf, lv;
    gates((float)hh[0], (float)ff[0], (float)ii[0], lf, lv);
    V0 = laddexp(V0 + lf, lv);
    gates((float)hh[1], (float)ff[1], (float)ii[1], lf, lv);
    V1 = laddexp(V1 + lf, lv);
    *(float2*)o = make_float2(__expf(V0), __expf(V1));
    o += DD;
    hh = hn; ff = fn; ii = in2;
  }
  float lf, lv;
  gates((float)hh[0], (float)ff[0], (float)ii[0], lf, lv);
  V0 = laddexp(V0 + lf, lv);
  gates((float)hh[1], (float)ff[1], (float)ii[1], lf, lv);
  V1 = laddexp(V1 + lf, lv);
  *(float2*)o = make_float2(__expf(V0), __expf(V1));
}

extern "C" void kernel_launch(void* const* d_in, const int* in_sizes, int n_in,
                              void* d_out, int out_size, void* d_ws,
                              size_t ws_size, hipStream_t stream) {
  const float* x = (const float*)d_in[0];
  const float* W = (const float*)d_in[1];
  float* out = (float*)d_out;
  char* ws = (char*)d_ws;

  // workspace layout: [Wt 6MB][xb 64MB][hW 192MB]; agg/pre (8MB each) overlay
  // the xb region, which is dead after the GEMM completes.
  const size_t wtB = (size_t)NN * KK * 2;   //  6,291,456
  const size_t xbB = (size_t)MM * KK * 2;   // 67,108,864
  const size_t aggB = (size_t)CHUNKS * NCH * sizeof(float2);  // 8 MiB
  bf16* Wt = (bf16*)ws;
  bf16* xb = (bf16*)(ws + wtB);
  bf16* hW = (bf16*)(ws + wtB + xbB);
  float2* agg = (float2*)(ws + wtB);          // overlays xb (dead post-GEMM)
  float2* pre = (float2*)(ws + wtB + aggB);

  k_cvt_wt<<<dim3(NN / 32, KK / 32), dim3(32, 8), 0, stream>>>(W, Wt);
  k_cvt_x<<<dim3(MM * KK / 4 / 256), dim3(256), 0, stream>>>((const float4*)x,
                                                             (bf16x4*)xb);
  k_gemm<<<dim3(NN / 128, MM / 128), 256, 0, stream>>>(xb, Wt, hW);
  k_scan1<<<dim3(DD / 512, BB, CHUNKS), 256, 0, stream>>>(hW, agg);
  k_scan2<<<dim3(NCH / 4), 256, 0, stream>>>(agg, pre);
  k_scan3<<<dim3(DD / 512, BB, CHUNKS), 256, 0, stream>>>(hW, pre, out);
}